// Round 2
// baseline (618.165 us; speedup 1.0000x reference)
//
#include <hip/hip_runtime.h>
#include <stdint.h>

typedef unsigned short u16;
typedef unsigned int u32;
typedef __attribute__((ext_vector_type(8))) short short8;
typedef __attribute__((ext_vector_type(4))) float floatx4;

// B=64, DIM=768, H=12, HEAD=64, SCALE=0.125
// xv: 64x784x768 f32, xa: 64x512x768 f32, xmm: 64x16x768 f32.

__device__ __forceinline__ u16 f2bf_rne(float f) {
  u32 u = __float_as_uint(f);
  return (u16)((u + 0x7fffu + ((u >> 16) & 1u)) >> 16);
}
// pack two f32 bit-patterns -> (bf16(a) | bf16(b)<<16)
__device__ __forceinline__ u32 pack_rne_u(u32 a, u32 b) {
  a += 0x7fffu + ((a >> 16) & 1u);
  b += 0x7fffu + ((b >> 16) & 1u);
  return __builtin_amdgcn_perm(b, a, 0x07060302u);
}
__device__ __forceinline__ void gld_lds16(const void* g, void* l) {
  __builtin_amdgcn_global_load_lds(
      (__attribute__((address_space(1))) void*)(uintptr_t)g,
      (__attribute__((address_space(3))) void*)l, 16, 0, 0);
}

// Raw barrier that does NOT drain vmcnt.
__device__ __forceinline__ void block_sync_lds() {
  asm volatile("s_waitcnt lgkmcnt(0)" ::: "memory");
  __builtin_amdgcn_s_barrier();
  asm volatile("" ::: "memory");
}

// ---------------------------------------------------------------------------
// Shared small-GEMM body: C = rowmap(A) @ W (+bias). W 768x768 row-major.
// ---------------------------------------------------------------------------
__device__ __forceinline__ void sg_body(
    float (*sAt)[20], float (*sW)[64],
    const float* __restrict__ A, int a_pitch, int a_rb, int a_off,
    const float* __restrict__ W, const float* __restrict__ bias,
    float* __restrict__ Cout, int c_pitch, int c_rb, int c_off,
    int rt, int n0)
{
  const int t = threadIdx.x;
  const int g = t >> 6;
  const int c = t & 63;

  float acc[4] = {0.f, 0.f, 0.f, 0.f};

  for (int ks = 0; ks < 12; ++ks) {
    {
      int r = t >> 4;
      int c4 = (t & 15) * 4;
      int lr = rt * 16 + r;
      int grow = (lr / a_rb) * a_pitch + a_off + (lr % a_rb);
      float4 v = *(const float4*)(A + (size_t)grow * 768 + ks * 64 + c4);
      sAt[c4 + 0][r] = v.x;
      sAt[c4 + 1][r] = v.y;
      sAt[c4 + 2][r] = v.z;
      sAt[c4 + 3][r] = v.w;
    }
#pragma unroll
    for (int u = 0; u < 4; ++u) {
      int unit = t + u * 256;
      int r = unit >> 4;
      int c4 = (unit & 15) * 4;
      *(float4*)&sW[r][c4] = *(const float4*)(W + (size_t)(ks * 64 + r) * 768 + n0 + c4);
    }
    __syncthreads();
#pragma unroll 8
    for (int k = 0; k < 64; ++k) {
      float4 a4 = *(const float4*)&sAt[k][g * 4];
      float w = sW[k][c];
      acc[0] += a4.x * w;
      acc[1] += a4.y * w;
      acc[2] += a4.z * w;
      acc[3] += a4.w * w;
    }
    __syncthreads();
  }

  float bs = bias ? bias[n0 + c] : 0.f;
#pragma unroll
  for (int rr = 0; rr < 4; ++rr) {
    int lr = rt * 16 + g * 4 + rr;
    int grow = (lr / c_rb) * c_pitch + c_off + (lr % c_rb);
    Cout[(size_t)grow * 768 + n0 + c] = acc[rr] + bs;
  }
}

// qproj: q_v / q_a / q_f in one launch. grid (64, 12).
__global__ __launch_bounds__(256) void qproj(
    const float* __restrict__ xmm,
    const float* __restrict__ qv_w, const float* __restrict__ qa_w,
    const float* __restrict__ fq_w,
    float* __restrict__ q_v, float* __restrict__ q_a, float* __restrict__ q_f)
{
  __shared__ float sAt[64][20];
  __shared__ float sW[64][64];
  int rt = blockIdx.x;
  int n0 = blockIdx.y * 64;
  if (rt < 16)
    sg_body(sAt, sW, xmm, 16, 4, 8, qv_w, nullptr, q_v, 4, 4, 0, rt, n0);
  else if (rt < 32)
    sg_body(sAt, sW, xmm, 16, 4, 12, qa_w, nullptr, q_a, 4, 4, 0, rt - 16, n0);
  else
    sg_body(sAt, sW, xmm, 16, 8, 0, fq_w, nullptr, q_f, 8, 8, 0, rt - 32, n0);
}

// proj v/a fused. grid (16, 12, 2).
__global__ __launch_bounds__(256) void proj2(
    const float* __restrict__ o_v, const float* __restrict__ o_a,
    const float* __restrict__ projv_w, const float* __restrict__ projv_b,
    const float* __restrict__ proja_w, const float* __restrict__ proja_b,
    float* __restrict__ out0)
{
  __shared__ float sAt[64][20];
  __shared__ float sW[64][64];
  int z = blockIdx.z;
  sg_body(sAt, sW, z ? o_a : o_v, 4, 4, 0,
          z ? proja_w : projv_w, z ? proja_b : projv_b,
          out0, 16, 4, z ? 12 : 8, blockIdx.x, blockIdx.y * 64);
}

// fkv: k1,k2,v1,v2 in one launch. grid (16, 12, 4). dsts contiguous.
__global__ __launch_bounds__(256) void fkv(
    const float* __restrict__ out0,
    const float* __restrict__ fk_w, const float* __restrict__ fv_w,
    float* __restrict__ kbase)
{
  __shared__ float sAt[64][20];
  __shared__ float sW[64][64];
  int z = blockIdx.z;
  const float* W = (z < 2) ? (fk_w + (size_t)(z & 1) * 768 * 768)
                           : (fv_w + (size_t)(z & 1) * 768 * 768);
  int a_off = (z & 1) ? 12 : 8;
  sg_body(sAt, sW, out0, 16, 4, a_off, W, nullptr,
          kbase + (size_t)z * 256 * 768, 4, 4, 0, blockIdx.x, blockIdx.y * 64);
}

// fproj. grid (32, 12).
__global__ __launch_bounds__(256) void fproj(
    const float* __restrict__ o_f,
    const float* __restrict__ fproj_w, const float* __restrict__ fproj_b,
    float* __restrict__ out0)
{
  __shared__ float sAt[64][20];
  __shared__ float sW[64][64];
  sg_body(sAt, sW, o_f, 8, 8, 0, fproj_w, fproj_b, out0, 16, 8, 0,
          blockIdx.x, blockIdx.y * 64);
}

// ---------------------------------------------------------------------------
// qtilde: Qt[b, h*4+qi, d] = sum_e q[b*4+qi, h*64+e] * kvw[d, h*64+e]  (bf16)
// grid (rt=16, nt=12, z=24): z = path*12 + h.
// ---------------------------------------------------------------------------
__global__ __launch_bounds__(256) void qtilde(
    const float* __restrict__ q_v, const float* __restrict__ q_a,
    const float* __restrict__ kvv_w, const float* __restrict__ kva_w,
    u16* __restrict__ Qt_v, u16* __restrict__ Qt_a)
{
  __shared__ float sAt[64][20];
  __shared__ float sW[64][65];

  const int rt = blockIdx.x;
  const int nt = blockIdx.y;
  const int path = blockIdx.z / 12;
  const int h = blockIdx.z % 12;
  const float* q = path ? q_a : q_v;
  const float* kvw = path ? kva_w : kvv_w;
  u16* Qt = path ? Qt_a : Qt_v;

  const int t = threadIdx.x;
  const int g = t >> 6;
  const int c = t & 63;
  const int n0 = nt * 64;

  {
    int r = t >> 4;
    int c4 = (t & 15) * 4;
    float4 v = *(const float4*)(q + (size_t)(rt * 16 + r) * 768 + h * 64 + c4);
    sAt[c4 + 0][r] = v.x;
    sAt[c4 + 1][r] = v.y;
    sAt[c4 + 2][r] = v.z;
    sAt[c4 + 3][r] = v.w;
  }
#pragma unroll
  for (int u = 0; u < 4; ++u) {
    int unit = t + u * 256;
    int d = unit >> 4;
    int c4 = (unit & 15) * 4;
    float4 v = *(const float4*)(kvw + (size_t)(n0 + d) * 1536 + h * 64 + c4);
    sW[d][c4 + 0] = v.x;
    sW[d][c4 + 1] = v.y;
    sW[d][c4 + 2] = v.z;
    sW[d][c4 + 3] = v.w;
  }
  __syncthreads();

  float acc[4] = {0.f, 0.f, 0.f, 0.f};
#pragma unroll 16
  for (int e = 0; e < 64; ++e) {
    float4 a4 = *(const float4*)&sAt[e][g * 4];
    float w = sW[c][e];
    acc[0] += a4.x * w;
    acc[1] += a4.y * w;
    acc[2] += a4.z * w;
    acc[3] += a4.w * w;
  }
#pragma unroll
  for (int rr = 0; rr < 4; ++rr) {
    int rl = rt * 16 + g * 4 + rr;
    Qt[((size_t)(rl >> 2) * 48 + h * 4 + (rl & 3)) * 768 + n0 + c] = f2bf_rne(acc[rr]);
  }
}

// ---------------------------------------------------------------------------
// attn_logits v3: contiguous-stream restructure.
// One wave (64 thr) per block owns 16 CONSECUTIVE X rows = one contiguous
// 48 KB block, staged as perfectly-coalesced linear dwordx4 loads (2-row
// chunks, ping-pong register buffers), packed bf16 into wave-private
// swizzled LDS, then 24 MFMA K-steps contracting the full 768 dims against
// Q fragments read per-lane from L2-hot Qt. No barriers anywhere.
// grid (81, 64): bx<49 -> v tile bx (49*16=784), else a tile bx-49 (32*16=512).
// ---------------------------------------------------------------------------
__global__ __launch_bounds__(64) void attn_logits(
    const u16* __restrict__ Qt_v, const u16* __restrict__ Qt_a,
    const float* __restrict__ Xv, const float* __restrict__ Xa,
    float* __restrict__ Sv, float* __restrict__ Sa)
{
  const int bx = blockIdx.x;
  const int b = blockIdx.y;
  const int isA = (bx >= 49);
  const int T = isA ? (bx - 49) : bx;
  const u16* Qt = isA ? Qt_a : Qt_v;
  const float* X = isA ? Xa : Xv;
  float* S = isA ? Sa : Sv;
  const int N2 = isA ? 512 : 784;

  __shared__ __align__(16) u16 sX[16 * 768];  // 24 KiB, swizzled

  const int lane = threadIdx.x;       // 0..63
  const int j0 = T * 16;
  const u32* Xt = (const u32*)(X + ((size_t)b * N2 + j0) * 768);  // 48KB contig
  const u16* Qb = Qt + (size_t)b * 48 * 768;
  const int ql = lane & 15;
  const int qs = lane >> 4;

  uint4 ra[6], rb[6];

  // chunk c = rows {2c, 2c+1} = 6 KB: lane's load i covers f32 idx
  // c*1536 + i*256 + lane*4 -> row jr = 2c + i/3, col = (i%3)*256 + lane*4.
#define L3_LOAD(buf, c_)                                                       \
  do {                                                                         \
    _Pragma("unroll") for (int i = 0; i < 6; ++i)                              \
      buf[i] = *(const uint4*)(Xt + (c_) * 1536 + i * 256 + lane * 4);         \
  } while (0)

#define L3_PACK(buf, c_)                                                       \
  do {                                                                         \
    _Pragma("unroll") for (int i = 0; i < 6; ++i) {                            \
      int jr_ = (c_) * 2 + i / 3;                                              \
      int colb_ = (i % 3) * 512 + lane * 8;                                    \
      uint2 w_;                                                                \
      w_.x = pack_rne_u(buf[i].x, buf[i].y);                                   \
      w_.y = pack_rne_u(buf[i].z, buf[i].w);                                   \
      *(uint2*)((char*)sX + jr_ * 1536 + (colb_ ^ ((jr_ & 7) << 4))) = w_;     \
    }                                                                          \
  } while (0)

  L3_LOAD(ra, 0);
#pragma unroll
  for (int c = 0; c < 8; ++c) {
    if (c + 1 < 8) {
      if (c & 1) L3_LOAD(ra, c + 1);
      else       L3_LOAD(rb, c + 1);
    }
    if (c & 1) L3_PACK(rb, c);
    else       L3_PACK(ra, c);
  }
#undef L3_LOAD
#undef L3_PACK
  // wave-private LDS: ds ops are in-order per wave; fence for the compiler.
  asm volatile("s_waitcnt lgkmcnt(0)" ::: "memory");

  floatx4 acc[3];
#pragma unroll
  for (int i = 0; i < 3; ++i) acc[i] = (floatx4){0.f, 0.f, 0.f, 0.f};

#pragma unroll 4
  for (int kk = 0; kk < 24; ++kk) {
    short8 bf = *(const short8*)((char*)sX + ql * 1536 +
                                 ((kk * 64 + qs * 16) ^ ((ql & 7) << 4)));
#pragma unroll
    for (int i = 0; i < 3; ++i) {
      short8 qa = *(const short8*)(Qb + (size_t)(i * 16 + ql) * 768 +
                                   kk * 32 + qs * 8);
      acc[i] = __builtin_amdgcn_mfma_f32_16x16x32_bf16(qa, bf, acc[i], 0, 0, 0);
    }
  }

#pragma unroll
  for (int i = 0; i < 3; ++i)
#pragma unroll
    for (int r = 0; r < 4; ++r)
      S[((size_t)b * 48 + i * 16 + qs * 4 + r) * N2 + j0 + ql] =
          acc[i][r] * 0.125f;
}

// ---------------------------------------------------------------------------
// softmax_p: P = softmax(S) bf16, zero-padded to N2p. grid (12, 64, 2).
// ---------------------------------------------------------------------------
__global__ __launch_bounds__(256) void softmax_p(
    const float* __restrict__ Sv, const float* __restrict__ Sa,
    u16* __restrict__ Pv, u16* __restrict__ Pa)
{
  const int z = blockIdx.z;
  const float* S = z ? Sa : Sv;
  u16* P = z ? Pa : Pv;
  const int N2 = z ? 512 : 784;
  const int N2p = z ? 512 : 832;

  const int hh = blockIdx.x;
  const int b = blockIdx.y;
  const int t = threadIdx.x;
  const int lane = t & 63;
  const int wave = t >> 6;
  const int row = hh * 4 + wave;
  const float* Srow = S + ((size_t)b * 48 + row) * N2;
  u16* Prow = P + ((size_t)b * 48 + row) * N2p;

  float m = -1e30f;
  for (int j = lane; j < N2; j += 64) m = fmaxf(m, Srow[j]);
#pragma unroll
  for (int off = 32; off > 0; off >>= 1) m = fmaxf(m, __shfl_xor(m, off));

  float e[13];
  float l = 0.f;
  int cnt = 0;
  for (int j = lane; j < N2; j += 64) {
    float p = __expf(Srow[j] - m);
    e[cnt++] = p;
    l += p;
  }
#pragma unroll
  for (int off = 32; off > 0; off >>= 1) l += __shfl_xor(l, off);
  float inv = 1.0f / l;

  cnt = 0;
  for (int j = lane; j < N2; j += 64) Prow[j] = f2bf_rne(e[cnt++] * inv);
  for (int j = N2 + lane; j < N2p; j += 64) Prow[j] = 0;
}

// ---------------------------------------------------------------------------
// attn_px: O[b,i,n] = (P_b @ X_b)[i,n]. grid (6, 64, 2).  (unchanged control)
// ---------------------------------------------------------------------------
__global__ __launch_bounds__(256) void attn_px(
    const u16* __restrict__ Pv, const u16* __restrict__ Pa,
    const float* __restrict__ Xv, const float* __restrict__ Xa,
    float* __restrict__ Ov, float* __restrict__ Oa)
{
  const int z = blockIdx.z;
  const u16* P = z ? Pa : Pv;
  const float* X = z ? Xa : Xv;
  float* O = z ? Oa : Ov;
  const int N2 = z ? 512 : 784;
  const int N2p = z ? 512 : 832;

  __shared__ __align__(16) u16 sXT[2][128 * 72];  // 36 KiB double-buffered

  const int t = threadIdx.x;
  const int lane = t & 63;
  const int wave = t >> 6;
  const int nt = blockIdx.x;
  const int b = blockIdx.y;
  const int n0 = nt * 128;
  const u16* Pb = P + (size_t)b * 48 * N2p;
  const float* Xb = X + (size_t)b * N2 * 768;
  const int Ks = N2p >> 6;

  const int jp0 = t >> 5;        // j-pair index (+ u*8)
  const int nq4 = (t & 31) * 4;  // n quad base
  const int qrow0 = lane & 15;
  const int qcb = (lane >> 4) * 8;

  floatx4 acc[3][2];
#pragma unroll
  for (int i = 0; i < 3; ++i)
#pragma unroll
    for (int j = 0; j < 2; ++j) acc[i][j] = (floatx4){0.f, 0.f, 0.f, 0.f};

  uint4 xA[4][2], xB[4][2];
  short8 qr[3][2];

#define PX_LOADX(dst, ks_)                                                     \
  do {                                                                         \
    _Pragma("unroll") for (int u = 0; u < 4; ++u) {                            \
      int j_ = (ks_) * 64 + (jp0 + u * 8) * 2;                                 \
      uint4 a0_ = {0u, 0u, 0u, 0u}, a1_ = {0u, 0u, 0u, 0u};                    \
      if (j_ < N2)                                                             \
        a0_ = *(const uint4*)(Xb + (size_t)j_ * 768 + n0 + nq4);               \
      if (j_ + 1 < N2)                                                         \
        a1_ = *(const uint4*)(Xb + (size_t)(j_ + 1) * 768 + n0 + nq4);         \
      dst[u][0] = a0_;                                                         \
      dst[u][1] = a1_;                                                         \
    }                                                                          \
  } while (0)

#define PX_LOADP(ks_)                                                          \
  do {                                                                         \
    _Pragma("unroll") for (int i = 0; i < 3; ++i)                              \
      _Pragma("unroll") for (int kk = 0; kk < 2; ++kk)                         \
        qr[i][kk] = *(const short8*)(Pb + (size_t)(i * 16 + qrow0) * N2p +     \
                                     (ks_) * 64 + kk * 32 + qcb);              \
  } while (0)

#define PX_WRITEX(src, bufp)                                                   \
  do {                                                                         \
    _Pragma("unroll") for (int u = 0; u < 4; ++u) {                            \
      int jl_ = (jp0 + u * 8) * 2;                                             \
      u32 w0_ = pack_rne_u(src[u][0].x, src[u][1].x);                          \
      u32 w1_ = pack_rne_u(src[u][0].y, src[u][1].y);                          \
      u32 w2_ = pack_rne_u(src[u][0].z, src[u][1].z);                          \
      u32 w3_ = pack_rne_u(src[u][0].w, src[u][1].w);                          \
      _Pragma("unroll") for (int m_ = 0; m_ < 4; ++m_) {                       \
        int n_ = nq4 + m_;                                                     \
        int sw_ = (((n_ >> 2) & 7) ^ ((n_ & 3) << 1)) * 8;                     \
        u32 wv_ = (m_ == 0) ? w0_ : (m_ == 1) ? w1_ : (m_ == 2) ? w2_ : w3_;   \
        *(u32*)((bufp) + n_ * 72 + (jl_ ^ sw_)) = wv_;                         \
      }                                                                        \
    }                                                                          \
  } while (0)

#define PX_COMPUTE(bufp)                                                       \
  do {                                                                         \
    _Pragma("unroll") for (int kk = 0; kk < 2; ++kk) {                         \
      _Pragma("unroll") for (int jj = 0; jj < 2; ++jj) {                       \
        int n_ = wave * 32 + jj * 16 + qrow0;                                  \
        int sw_ = (((n_ >> 2) & 7) ^ ((n_ & 3) << 1)) * 8;                     \
        int kb_ = kk * 32 + qcb;                                               \
        short8 bfr_ = *(const short8*)((bufp) + n_ * 72 + (kb_ ^ sw_));        \
        _Pragma("unroll") for (int i = 0; i < 3; ++i)                          \
          acc[i][jj] = __builtin_amdgcn_mfma_f32_16x16x32_bf16(                \
              qr[i][kk], bfr_, acc[i][jj], 0, 0, 0);                           \
      }                                                                        \
    }                                                                          \
  } while (0)

  u16* sT0 = &sXT[0][0];
  u16* sT1 = &sXT[1][0];

  PX_LOADX(xA, 0);
  PX_LOADP(0);
  int ks = 0;
  for (;;) {
    int more0 = (ks + 1 < Ks);
    if (more0) PX_LOADX(xB, ks + 1);
    PX_WRITEX(xA, sT0);
    block_sync_lds();
    PX_COMPUTE(sT0);
    if (!more0) break;
    PX_LOADP(ks + 1);
    ++ks;
    int more1 = (ks + 1 < Ks);
    if (more1) PX_LOADX(xA, ks + 1);
    PX_WRITEX(xB, sT1);
    block_sync_lds();
    PX_COMPUTE(sT1);
    if (!more1) break;
    PX_LOADP(ks + 1);
    ++ks;
  }
#undef PX_LOADX
#undef PX_LOADP
#undef PX_WRITEX
#undef PX_COMPUTE

  const int quad = lane >> 4;
  const int lc = lane & 15;
#pragma unroll
  for (int i = 0; i < 3; ++i)
#pragma unroll
    for (int jj = 0; jj < 2; ++jj) {
      int col = n0 + wave * 32 + jj * 16 + lc;
      int row0 = i * 16 + quad * 4;
#pragma unroll
      for (int r = 0; r < 4; ++r)
        O[((size_t)b * 48 + row0 + r) * 768 + col] = acc[i][jj][r];
    }
}

// ---------------------------------------------------------------------------
// omix: o[b*4+qi, h*64+e] = sum_d O[b*48+h*4+qi, d] * kvw[d, 768+h*64+e]
// grid (16, 12, 2).
// ---------------------------------------------------------------------------
__global__ __launch_bounds__(256) void omix(
    const float* __restrict__ O_v, const float* __restrict__ O_a,
    const float* __restrict__ kvv_w, const float* __restrict__ kva_w,
    float* __restrict__ o_v, float* __restrict__ o_a)
{
  __shared__ float sAt[64][20];
  __shared__ float sW[64][64];

  const int z = blockIdx.z;
  const float* Ob = z ? O_a : O_v;
  const float* kvw = z ? kva_w : kvv_w;
  float* oo = z ? o_a : o_v;

  const int rt = blockIdx.x;
  const int h = blockIdx.y;
  const int t = threadIdx.x;
  const int g = t >> 6;
  const int c = t & 63;

  float acc[4] = {0.f, 0.f, 0.f, 0.f};

  for (int ks = 0; ks < 12; ++ks) {
    {
      int r = t >> 4;
      int c4 = (t & 15) * 4;
      int rl = rt * 16 + r;
      int arow = (rl >> 2) * 48 + h * 4 + (rl & 3);
      float4 v = *(const float4*)(Ob + (size_t)arow * 768 + ks * 64 + c4);
      sAt[c4 + 0][r] = v.x;
      sAt[c4 + 1][r] = v.y;
      sAt[c4 + 2][r] = v.z;
      sAt[c4 + 3][r] = v.w;
    }
#pragma unroll
    for (int u = 0; u < 4; ++u) {
      int unit = t + u * 256;
      int k = unit >> 4;
      int c4 = (unit & 15) * 4;
      *(float4*)&sW[k][c4] = *(const float4*)(kvw + (size_t)(ks * 64 + k) * 1536 + 768 + h * 64 + c4);
    }
    __syncthreads();
#pragma unroll 8
    for (int k = 0; k < 64; ++k) {
      float4 a4 = *(const float4*)&sAt[k][g * 4];
      float w = sW[k][c];
      acc[0] += a4.x * w;
      acc[1] += a4.y * w;
      acc[2] += a4.z * w;
      acc[3] += a4.w * w;
    }
    __syncthreads();
  }

#pragma unroll
  for (int rr = 0; rr < 4; ++rr) {
    int rl = rt * 16 + g * 4 + rr;
    oo[(size_t)rl * 768 + h * 64 + c] = acc[rr];
  }
}

// ---------------------------------------------------------------------------
// Fusion attention. grid (12, 64).
// ---------------------------------------------------------------------------
__global__ __launch_bounds__(256) void fusion_attn(
    const float* __restrict__ Qf,
    const float* __restrict__ K1, const float* __restrict__ K2,
    const float* __restrict__ V1, const float* __restrict__ V2,
    float* __restrict__ Of,
    float* __restrict__ AttnOut)
{
  const int h = blockIdx.x;
  const int b = blockIdx.y;
  const int t = threadIdx.x;
  const int lane = t & 63;
  const int wave = t >> 6;

  __shared__ float sQ[8][64];
  __shared__ float sK1[4][64], sK2[4][64], sV1[4][64], sV2[4][64];
  __shared__ float sP[8][16];

  for (int idx = t; idx < 512; idx += 256)
    sQ[idx >> 6][idx & 63] = Qf[((size_t)(b * 8 + (idx >> 6))) * 768 + h * 64 + (idx & 63)];
  {
    size_t base = ((size_t)(b * 4 + wave)) * 768 + h * 64 + lane;
    sK1[wave][lane] = K1[base];
    sK2[wave][lane] = K2[base];
    sV1[wave][lane] = V1[base];
    sV2[wave][lane] = V2[base];
  }
  __syncthreads();

  if (t < 128) {
    int qi = t >> 4, m = t & 15, iv = m >> 2, ja = m & 3;
    float s = 0.f;
#pragma unroll
    for (int d = 0; d < 64; ++d) s += sQ[qi][d] * (sK1[iv][d] + sK2[ja][d]);
    s *= 0.125f;
    float mx = s;
#pragma unroll
    for (int off = 8; off > 0; off >>= 1) mx = fmaxf(mx, __shfl_xor(mx, off, 16));
    float p = __expf(s - mx);
    float l = p;
#pragma unroll
    for (int off = 8; off > 0; off >>= 1) l += __shfl_xor(l, off, 16);
    p = p / l;
    sP[qi][m] = p;
    AttnOut[(((size_t)b * 12 + h) * 8 + qi) * 16 + m] = p;
  }
  __syncthreads();

  for (int idx = t; idx < 512; idx += 256) {
    int qi = idx >> 6, d = idx & 63;
    float o = 0.f;
#pragma unroll
    for (int m = 0; m < 16; ++m) o += sP[qi][m] * (sV1[m >> 2][d] + sV2[m & 3][d]);
    Of[((size_t)(b * 8 + qi)) * 768 + h * 64 + d] = o;
  }
}

// ---------------------------------------------------------------------------
extern "C" void kernel_launch(void* const* d_in, const int* in_sizes, int n_in,
                              void* d_out, int out_size, void* d_ws, size_t ws_size,
                              hipStream_t stream)
{
  const float* xmm     = (const float*)d_in[0];
  const float* xv      = (const float*)d_in[1];
  const float* xa      = (const float*)d_in[2];
  const float* qv_w    = (const float*)d_in[3];
  const float* kvv_w   = (const float*)d_in[4];
  const float* projv_w = (const float*)d_in[5];
  const float* projv_b = (const float*)d_in[6];
  const float* qa_w    = (const float*)d_in[7];
  const float* kva_w   = (const float*)d_in[8];
  const float* proja_w = (const float*)d_in[9];
  const float* proja_b = (const float*)d_in[10];
  const float* fq_w    = (const float*)d_in[11];
  const float* fk_w    = (const float*)d_in[12];
  const float* fv_w    = (const float*)d_in[13];
  const float* fproj_w = (const float*)d_in[14];
  const float* fproj_b = (const float*)d_in[15];

  float* out0 = (float*)d_out;                       // 64 x 16 x 768
  float* out1 = out0 + (size_t)64 * 16 * 768;        // 64 x 12 x 8 x 16

  char* ws = (char*)d_ws;
  size_t off = 0;
  float* q_v  = (float*)(ws + off); off += (size_t)256 * 768 * 4;
  float* q_a  = (float*)(ws + off); off += (size_t)256 * 768 * 4;
  float* q_f  = (float*)(ws + off); off += (size_t)512 * 768 * 4;
  u16*   Qt_v = (u16*)(ws + off);   off += (size_t)64 * 48 * 768 * 2;
  u16*   Qt_a = (u16*)(ws + off);   off += (size_t)64 * 48 * 768 * 2;
  float* S_v  = (float*)(ws + off); off += (size_t)64 * 48 * 784 * 4;
  float* S_a  = (float*)(ws + off); off += (size_t)64 * 48 * 512 * 4;
  u16*   P_v  = (u16*)(ws + off);   off += (size_t)64 * 48 * 832 * 2;
  u16*   P_a  = (u16*)(ws + off);   off += (size_t)64 * 48 * 512 * 2;
  float* O_v  = (float*)(ws + off); off += (size_t)64 * 48 * 768 * 4;
  float* O_a  = (float*)(ws + off); off += (size_t)64 * 48 * 768 * 4;
  float* o_v  = (float*)(ws + off); off += (size_t)256 * 768 * 4;
  float* o_a  = (float*)(ws + off); off += (size_t)256 * 768 * 4;
  float* kbase = (float*)(ws + off); off += (size_t)4 * 256 * 768 * 4;  // k1,k2,v1,v2
  float* o_f  = (float*)(ws + off); off += (size_t)512 * 768 * 4;

  float* k1 = kbase;
  float* k2 = kbase + (size_t)256 * 768;
  float* v1 = kbase + (size_t)2 * 256 * 768;
  float* v2 = kbase + (size_t)3 * 256 * 768;

  qproj<<<dim3(64, 12), 256, 0, stream>>>(xmm, qv_w, qa_w, fq_w, q_v, q_a, q_f);
  qtilde<<<dim3(16, 12, 24), 256, 0, stream>>>(q_v, q_a, kvv_w, kva_w, Qt_v, Qt_a);
  attn_logits<<<dim3(81, 64), 64, 0, stream>>>(Qt_v, Qt_a, xv, xa, S_v, S_a);
  softmax_p<<<dim3(12, 64, 2), 256, 0, stream>>>(S_v, S_a, P_v, P_a);
  attn_px<<<dim3(6, 64, 2), 256, 0, stream>>>(P_v, P_a, xv, xa, O_v, O_a);
  omix<<<dim3(16, 12, 2), 256, 0, stream>>>(O_v, O_a, kvv_w, kva_w, o_v, o_a);
  proj2<<<dim3(16, 12, 2), 256, 0, stream>>>(o_v, o_a, projv_w, projv_b, proja_w, proja_b, out0);
  fkv<<<dim3(16, 12, 4), 256, 0, stream>>>(out0, fk_w, fv_w, kbase);
  fusion_attn<<<dim3(12, 64), 256, 0, stream>>>(q_f, k1, k2, v1, v2, o_f, out1);
  fproj<<<dim3(32, 12), 256, 0, stream>>>(o_f, fproj_w, fproj_b, out0);
}

// Round 3
// 608.249 us; speedup vs baseline: 1.0163x; 1.0163x over previous
//
#include <hip/hip_runtime.h>
#include <stdint.h>

typedef unsigned short u16;
typedef unsigned int u32;
typedef __attribute__((ext_vector_type(8))) short short8;
typedef __attribute__((ext_vector_type(4))) float floatx4;

// B=64, DIM=768, H=12, HEAD=64, SCALE=0.125
// xv: 64x784x768 f32, xa: 64x512x768 f32, xmm: 64x16x768 f32.

__device__ __forceinline__ u16 f2bf_rne(float f) {
  u32 u = __float_as_uint(f);
  return (u16)((u + 0x7fffu + ((u >> 16) & 1u)) >> 16);
}
// pack two f32 bit-patterns -> (bf16(a) | bf16(b)<<16)
__device__ __forceinline__ u32 pack_rne_u(u32 a, u32 b) {
  a += 0x7fffu + ((a >> 16) & 1u);
  b += 0x7fffu + ((b >> 16) & 1u);
  return __builtin_amdgcn_perm(b, a, 0x07060302u);
}
// 8 f32 (two uint4 bit-pattern vectors) -> short8 of bf16
__device__ __forceinline__ short8 pack8(uint4 a, uint4 b) {
  union { u32 u[4]; short8 s; } cv;
  cv.u[0] = pack_rne_u(a.x, a.y);
  cv.u[1] = pack_rne_u(a.z, a.w);
  cv.u[2] = pack_rne_u(b.x, b.y);
  cv.u[3] = pack_rne_u(b.z, b.w);
  return cv.s;
}

// Raw barrier that does NOT drain vmcnt.
__device__ __forceinline__ void block_sync_lds() {
  asm volatile("s_waitcnt lgkmcnt(0)" ::: "memory");
  __builtin_amdgcn_s_barrier();
  asm volatile("" ::: "memory");
}

// ---------------------------------------------------------------------------
// Shared small-GEMM body: C = rowmap(A) @ W (+bias). W 768x768 row-major.
// ---------------------------------------------------------------------------
__device__ __forceinline__ void sg_body(
    float (*sAt)[20], float (*sW)[64],
    const float* __restrict__ A, int a_pitch, int a_rb, int a_off,
    const float* __restrict__ W, const float* __restrict__ bias,
    float* __restrict__ Cout, int c_pitch, int c_rb, int c_off,
    int rt, int n0)
{
  const int t = threadIdx.x;
  const int g = t >> 6;
  const int c = t & 63;

  float acc[4] = {0.f, 0.f, 0.f, 0.f};

  for (int ks = 0; ks < 12; ++ks) {
    {
      int r = t >> 4;
      int c4 = (t & 15) * 4;
      int lr = rt * 16 + r;
      int grow = (lr / a_rb) * a_pitch + a_off + (lr % a_rb);
      float4 v = *(const float4*)(A + (size_t)grow * 768 + ks * 64 + c4);
      sAt[c4 + 0][r] = v.x;
      sAt[c4 + 1][r] = v.y;
      sAt[c4 + 2][r] = v.z;
      sAt[c4 + 3][r] = v.w;
    }
#pragma unroll
    for (int u = 0; u < 4; ++u) {
      int unit = t + u * 256;
      int r = unit >> 4;
      int c4 = (unit & 15) * 4;
      *(float4*)&sW[r][c4] = *(const float4*)(W + (size_t)(ks * 64 + r) * 768 + n0 + c4);
    }
    __syncthreads();
#pragma unroll 8
    for (int k = 0; k < 64; ++k) {
      float4 a4 = *(const float4*)&sAt[k][g * 4];
      float w = sW[k][c];
      acc[0] += a4.x * w;
      acc[1] += a4.y * w;
      acc[2] += a4.z * w;
      acc[3] += a4.w * w;
    }
    __syncthreads();
  }

  float bs = bias ? bias[n0 + c] : 0.f;
#pragma unroll
  for (int rr = 0; rr < 4; ++rr) {
    int lr = rt * 16 + g * 4 + rr;
    int grow = (lr / c_rb) * c_pitch + c_off + (lr % c_rb);
    Cout[(size_t)grow * 768 + n0 + c] = acc[rr] + bs;
  }
}

// qproj: q_v / q_a / q_f in one launch. grid (64, 12).
__global__ __launch_bounds__(256) void qproj(
    const float* __restrict__ xmm,
    const float* __restrict__ qv_w, const float* __restrict__ qa_w,
    const float* __restrict__ fq_w,
    float* __restrict__ q_v, float* __restrict__ q_a, float* __restrict__ q_f)
{
  __shared__ float sAt[64][20];
  __shared__ float sW[64][64];
  int rt = blockIdx.x;
  int n0 = blockIdx.y * 64;
  if (rt < 16)
    sg_body(sAt, sW, xmm, 16, 4, 8, qv_w, nullptr, q_v, 4, 4, 0, rt, n0);
  else if (rt < 32)
    sg_body(sAt, sW, xmm, 16, 4, 12, qa_w, nullptr, q_a, 4, 4, 0, rt - 16, n0);
  else
    sg_body(sAt, sW, xmm, 16, 8, 0, fq_w, nullptr, q_f, 8, 8, 0, rt - 32, n0);
}

// proj v/a fused. grid (16, 12, 2).
__global__ __launch_bounds__(256) void proj2(
    const float* __restrict__ o_v, const float* __restrict__ o_a,
    const float* __restrict__ projv_w, const float* __restrict__ projv_b,
    const float* __restrict__ proja_w, const float* __restrict__ proja_b,
    float* __restrict__ out0)
{
  __shared__ float sAt[64][20];
  __shared__ float sW[64][64];
  int z = blockIdx.z;
  sg_body(sAt, sW, z ? o_a : o_v, 4, 4, 0,
          z ? proja_w : projv_w, z ? proja_b : projv_b,
          out0, 16, 4, z ? 12 : 8, blockIdx.x, blockIdx.y * 64);
}

// fkv: k1,k2,v1,v2 in one launch. grid (16, 12, 4). dsts contiguous.
__global__ __launch_bounds__(256) void fkv(
    const float* __restrict__ out0,
    const float* __restrict__ fk_w, const float* __restrict__ fv_w,
    float* __restrict__ kbase)
{
  __shared__ float sAt[64][20];
  __shared__ float sW[64][64];
  int z = blockIdx.z;
  const float* W = (z < 2) ? (fk_w + (size_t)(z & 1) * 768 * 768)
                           : (fv_w + (size_t)(z & 1) * 768 * 768);
  int a_off = (z & 1) ? 12 : 8;
  sg_body(sAt, sW, out0, 16, 4, a_off, W, nullptr,
          kbase + (size_t)z * 256 * 768, 4, 4, 0, blockIdx.x, blockIdx.y * 64);
}

// fproj. grid (32, 12).
__global__ __launch_bounds__(256) void fproj(
    const float* __restrict__ o_f,
    const float* __restrict__ fproj_w, const float* __restrict__ fproj_b,
    float* __restrict__ out0)
{
  __shared__ float sAt[64][20];
  __shared__ float sW[64][64];
  sg_body(sAt, sW, o_f, 8, 8, 0, fproj_w, fproj_b, out0, 16, 8, 0,
          blockIdx.x, blockIdx.y * 64);
}

// ---------------------------------------------------------------------------
// qtilde: Qt[b, h*4+qi, d] = sum_e q[b*4+qi, h*64+e] * kvw[d, h*64+e]  (bf16)
// grid (rt=16, nt=12, z=24): z = path*12 + h.
// ---------------------------------------------------------------------------
__global__ __launch_bounds__(256) void qtilde(
    const float* __restrict__ q_v, const float* __restrict__ q_a,
    const float* __restrict__ kvv_w, const float* __restrict__ kva_w,
    u16* __restrict__ Qt_v, u16* __restrict__ Qt_a)
{
  __shared__ float sAt[64][20];
  __shared__ float sW[64][65];

  const int rt = blockIdx.x;
  const int nt = blockIdx.y;
  const int path = blockIdx.z / 12;
  const int h = blockIdx.z % 12;
  const float* q = path ? q_a : q_v;
  const float* kvw = path ? kva_w : kvv_w;
  u16* Qt = path ? Qt_a : Qt_v;

  const int t = threadIdx.x;
  const int g = t >> 6;
  const int c = t & 63;
  const int n0 = nt * 64;

  {
    int r = t >> 4;
    int c4 = (t & 15) * 4;
    float4 v = *(const float4*)(q + (size_t)(rt * 16 + r) * 768 + h * 64 + c4);
    sAt[c4 + 0][r] = v.x;
    sAt[c4 + 1][r] = v.y;
    sAt[c4 + 2][r] = v.z;
    sAt[c4 + 3][r] = v.w;
  }
#pragma unroll
  for (int u = 0; u < 4; ++u) {
    int unit = t + u * 256;
    int d = unit >> 4;
    int c4 = (unit & 15) * 4;
    float4 v = *(const float4*)(kvw + (size_t)(n0 + d) * 1536 + h * 64 + c4);
    sW[d][c4 + 0] = v.x;
    sW[d][c4 + 1] = v.y;
    sW[d][c4 + 2] = v.z;
    sW[d][c4 + 3] = v.w;
  }
  __syncthreads();

  float acc[4] = {0.f, 0.f, 0.f, 0.f};
#pragma unroll 16
  for (int e = 0; e < 64; ++e) {
    float4 a4 = *(const float4*)&sAt[e][g * 4];
    float w = sW[c][e];
    acc[0] += a4.x * w;
    acc[1] += a4.y * w;
    acc[2] += a4.z * w;
    acc[3] += a4.w * w;
  }
#pragma unroll
  for (int rr = 0; rr < 4; ++rr) {
    int rl = rt * 16 + g * 4 + rr;
    Qt[((size_t)(rl >> 2) * 48 + h * 4 + (rl & 3)) * 768 + n0 + c] = f2bf_rne(acc[rr]);
  }
}

// ---------------------------------------------------------------------------
// attn_logits v4: LDS-free direct-MFMA.
// Each lane loads its X B-fragment (8 consecutive f32) straight from global,
// packs to bf16 in-register, feeds MFMA. No LDS, no barriers -> waves
// free-run; occupancy VGPR-bound; per-kk addresses are compile-time
// offset immediates (kk*128B < 4096). X read exactly once per block.
// grid (7, 64, 2); j-tail rows clamped (stores guarded by col<N2).
// ---------------------------------------------------------------------------
__global__ __launch_bounds__(256) void attn_logits(
    const u16* __restrict__ Qt_v, const u16* __restrict__ Qt_a,
    const float* __restrict__ Xv, const float* __restrict__ Xa,
    float* __restrict__ Sv, float* __restrict__ Sa)
{
  const int z = blockIdx.z;
  const int jt = blockIdx.x;
  if (z == 1 && jt >= 4) return;
  const u16* Qt = z ? Qt_a : Qt_v;
  const float* X = z ? Xa : Xv;
  float* S = z ? Sa : Sv;
  const int N2 = z ? 512 : 784;

  const int t = threadIdx.x;
  const int lane = t & 63;
  const int wave = t >> 6;
  const int b = blockIdx.y;
  const int j0 = jt * 128;
  const u16* Qb = Qt + (size_t)b * 48 * 768;
  const float* Xb = X + (size_t)b * N2 * 768;

  const int ql = lane & 15;
  const int qs = lane >> 4;

  int row0 = j0 + wave * 32 + ql;   // jj = 0
  int row1 = row0 + 16;             // jj = 1
  if (row0 > N2 - 1) row0 = N2 - 1;
  if (row1 > N2 - 1) row1 = N2 - 1;
  const float* xP0 = Xb + (size_t)row0 * 768 + qs * 8;
  const float* xP1 = Xb + (size_t)row1 * 768 + qs * 8;
  const u16* qP0 = Qb + (size_t)(0 * 16 + ql) * 768 + qs * 8;
  const u16* qP1 = Qb + (size_t)(1 * 16 + ql) * 768 + qs * 8;
  const u16* qP2 = Qb + (size_t)(2 * 16 + ql) * 768 + qs * 8;

  floatx4 acc[3][2];
#pragma unroll
  for (int i = 0; i < 3; ++i)
#pragma unroll
    for (int j = 0; j < 2; ++j) acc[i][j] = (floatx4){0.f, 0.f, 0.f, 0.f};

#pragma unroll 4
  for (int kk = 0; kk < 24; ++kk) {
    uint4 x0a = *(const uint4*)(xP0 + kk * 32);
    uint4 x0b = *(const uint4*)(xP0 + kk * 32 + 4);
    uint4 x1a = *(const uint4*)(xP1 + kk * 32);
    uint4 x1b = *(const uint4*)(xP1 + kk * 32 + 4);
    short8 qa0 = *(const short8*)(qP0 + kk * 32);
    short8 qa1 = *(const short8*)(qP1 + kk * 32);
    short8 qa2 = *(const short8*)(qP2 + kk * 32);
    short8 bf0 = pack8(x0a, x0b);
    short8 bf1 = pack8(x1a, x1b);
    acc[0][0] = __builtin_amdgcn_mfma_f32_16x16x32_bf16(qa0, bf0, acc[0][0], 0, 0, 0);
    acc[0][1] = __builtin_amdgcn_mfma_f32_16x16x32_bf16(qa0, bf1, acc[0][1], 0, 0, 0);
    acc[1][0] = __builtin_amdgcn_mfma_f32_16x16x32_bf16(qa1, bf0, acc[1][0], 0, 0, 0);
    acc[1][1] = __builtin_amdgcn_mfma_f32_16x16x32_bf16(qa1, bf1, acc[1][1], 0, 0, 0);
    acc[2][0] = __builtin_amdgcn_mfma_f32_16x16x32_bf16(qa2, bf0, acc[2][0], 0, 0, 0);
    acc[2][1] = __builtin_amdgcn_mfma_f32_16x16x32_bf16(qa2, bf1, acc[2][1], 0, 0, 0);
  }

  const int quad = lane >> 4;
  const int lc = lane & 15;
#pragma unroll
  for (int i = 0; i < 3; ++i)
#pragma unroll
    for (int jj = 0; jj < 2; ++jj) {
      int col = j0 + wave * 32 + jj * 16 + lc;
      if (col < N2) {
        int row0s = i * 16 + quad * 4;
#pragma unroll
        for (int r = 0; r < 4; ++r)
          S[((size_t)b * 48 + row0s + r) * N2 + col] = acc[i][jj][r] * 0.125f;
      }
    }
}

// ---------------------------------------------------------------------------
// softmax_p: P = softmax(S) bf16, zero-padded to N2p. grid (12, 64, 2).
// ---------------------------------------------------------------------------
__global__ __launch_bounds__(256) void softmax_p(
    const float* __restrict__ Sv, const float* __restrict__ Sa,
    u16* __restrict__ Pv, u16* __restrict__ Pa)
{
  const int z = blockIdx.z;
  const float* S = z ? Sa : Sv;
  u16* P = z ? Pa : Pv;
  const int N2 = z ? 512 : 784;
  const int N2p = z ? 512 : 832;

  const int hh = blockIdx.x;
  const int b = blockIdx.y;
  const int t = threadIdx.x;
  const int lane = t & 63;
  const int wave = t >> 6;
  const int row = hh * 4 + wave;
  const float* Srow = S + ((size_t)b * 48 + row) * N2;
  u16* Prow = P + ((size_t)b * 48 + row) * N2p;

  float m = -1e30f;
  for (int j = lane; j < N2; j += 64) m = fmaxf(m, Srow[j]);
#pragma unroll
  for (int off = 32; off > 0; off >>= 1) m = fmaxf(m, __shfl_xor(m, off));

  float e[13];
  float l = 0.f;
  int cnt = 0;
  for (int j = lane; j < N2; j += 64) {
    float p = __expf(Srow[j] - m);
    e[cnt++] = p;
    l += p;
  }
#pragma unroll
  for (int off = 32; off > 0; off >>= 1) l += __shfl_xor(l, off);
  float inv = 1.0f / l;

  cnt = 0;
  for (int j = lane; j < N2; j += 64) Prow[j] = f2bf_rne(e[cnt++] * inv);
  for (int j = N2 + lane; j < N2p; j += 64) Prow[j] = 0;
}

// ---------------------------------------------------------------------------
// attn_px: O[b,i,n] = (P_b @ X_b)[i,n]. grid (6, 64, 2).  (unchanged control)
// ---------------------------------------------------------------------------
__global__ __launch_bounds__(256) void attn_px(
    const u16* __restrict__ Pv, const u16* __restrict__ Pa,
    const float* __restrict__ Xv, const float* __restrict__ Xa,
    float* __restrict__ Ov, float* __restrict__ Oa)
{
  const int z = blockIdx.z;
  const u16* P = z ? Pa : Pv;
  const float* X = z ? Xa : Xv;
  float* O = z ? Oa : Ov;
  const int N2 = z ? 512 : 784;
  const int N2p = z ? 512 : 832;

  __shared__ __align__(16) u16 sXT[2][128 * 72];  // 36 KiB double-buffered

  const int t = threadIdx.x;
  const int lane = t & 63;
  const int wave = t >> 6;
  const int nt = blockIdx.x;
  const int b = blockIdx.y;
  const int n0 = nt * 128;
  const u16* Pb = P + (size_t)b * 48 * N2p;
  const float* Xb = X + (size_t)b * N2 * 768;
  const int Ks = N2p >> 6;

  const int jp0 = t >> 5;        // j-pair index (+ u*8)
  const int nq4 = (t & 31) * 4;  // n quad base
  const int qrow0 = lane & 15;
  const int qcb = (lane >> 4) * 8;

  floatx4 acc[3][2];
#pragma unroll
  for (int i = 0; i < 3; ++i)
#pragma unroll
    for (int j = 0; j < 2; ++j) acc[i][j] = (floatx4){0.f, 0.f, 0.f, 0.f};

  uint4 xA[4][2], xB[4][2];
  short8 qr[3][2];

#define PX_LOADX(dst, ks_)                                                     \
  do {                                                                         \
    _Pragma("unroll") for (int u = 0; u < 4; ++u) {                            \
      int j_ = (ks_) * 64 + (jp0 + u * 8) * 2;                                 \
      uint4 a0_ = {0u, 0u, 0u, 0u}, a1_ = {0u, 0u, 0u, 0u};                    \
      if (j_ < N2)                                                             \
        a0_ = *(const uint4*)(Xb + (size_t)j_ * 768 + n0 + nq4);               \
      if (j_ + 1 < N2)                                                         \
        a1_ = *(const uint4*)(Xb + (size_t)(j_ + 1) * 768 + n0 + nq4);         \
      dst[u][0] = a0_;                                                         \
      dst[u][1] = a1_;                                                         \
    }                                                                          \
  } while (0)

#define PX_LOADP(ks_)                                                          \
  do {                                                                         \
    _Pragma("unroll") for (int i = 0; i < 3; ++i)                              \
      _Pragma("unroll") for (int kk = 0; kk < 2; ++kk)                         \
        qr[i][kk] = *(const short8*)(Pb + (size_t)(i * 16 + qrow0) * N2p +     \
                                     (ks_) * 64 + kk * 32 + qcb);              \
  } while (0)

#define PX_WRITEX(src, bufp)                                                   \
  do {                                                                         \
    _Pragma("unroll") for (int u = 0; u < 4; ++u) {                            \
      int jl_ = (jp0 + u * 8) * 2;                                             \
      u32 w0_ = pack_rne_u(src[u][0].x, src[u][1].x);                          \
      u32 w1_ = pack_rne_u(src[u][0].y, src[u][1].y);                          \
      u32 w2_ = pack_rne_u(src[u][0].z, src[u][1].z);                          \
      u32 w3_ = pack_rne_u(src[u][0].w, src[u][1].w);                          \
      _Pragma("unroll") for (int m_ = 0; m_ < 4; ++m_) {                       \
        int n_ = nq4 + m_;                                                     \
        int sw_ = (((n_ >> 2) & 7) ^ ((n_ & 3) << 1)) * 8;                     \
        u32 wv_ = (m_ == 0) ? w0_ : (m_ == 1) ? w1_ : (m_ == 2) ? w2_ : w3_;   \
        *(u32*)((bufp) + n_ * 72 + (jl_ ^ sw_)) = wv_;                         \
      }                                                                        \
    }                                                                          \
  } while (0)

#define PX_COMPUTE(bufp)                                                       \
  do {                                                                         \
    _Pragma("unroll") for (int kk = 0; kk < 2; ++kk) {                         \
      _Pragma("unroll") for (int jj = 0; jj < 2; ++jj) {                       \
        int n_ = wave * 32 + jj * 16 + qrow0;                                  \
        int sw_ = (((n_ >> 2) & 7) ^ ((n_ & 3) << 1)) * 8;                     \
        int kb_ = kk * 32 + qcb;                                               \
        short8 bfr_ = *(const short8*)((bufp) + n_ * 72 + (kb_ ^ sw_));        \
        _Pragma("unroll") for (int i = 0; i < 3; ++i)                          \
          acc[i][jj] = __builtin_amdgcn_mfma_f32_16x16x32_bf16(                \
              qr[i][kk], bfr_, acc[i][jj], 0, 0, 0);                           \
      }                                                                        \
    }                                                                          \
  } while (0)

  u16* sT0 = &sXT[0][0];
  u16* sT1 = &sXT[1][0];

  PX_LOADX(xA, 0);
  PX_LOADP(0);
  int ks = 0;
  for (;;) {
    int more0 = (ks + 1 < Ks);
    if (more0) PX_LOADX(xB, ks + 1);
    PX_WRITEX(xA, sT0);
    block_sync_lds();
    PX_COMPUTE(sT0);
    if (!more0) break;
    PX_LOADP(ks + 1);
    ++ks;
    int more1 = (ks + 1 < Ks);
    if (more1) PX_LOADX(xA, ks + 1);
    PX_WRITEX(xB, sT1);
    block_sync_lds();
    PX_COMPUTE(sT1);
    if (!more1) break;
    PX_LOADP(ks + 1);
    ++ks;
  }
#undef PX_LOADX
#undef PX_LOADP
#undef PX_WRITEX
#undef PX_COMPUTE

  const int quad = lane >> 4;
  const int lc = lane & 15;
#pragma unroll
  for (int i = 0; i < 3; ++i)
#pragma unroll
    for (int jj = 0; jj < 2; ++jj) {
      int col = n0 + wave * 32 + jj * 16 + lc;
      int row0 = i * 16 + quad * 4;
#pragma unroll
      for (int r = 0; r < 4; ++r)
        O[((size_t)b * 48 + row0 + r) * 768 + col] = acc[i][jj][r];
    }
}

// ---------------------------------------------------------------------------
// omix: o[b*4+qi, h*64+e] = sum_d O[b*48+h*4+qi, d] * kvw[d, 768+h*64+e]
// grid (16, 12, 2).
// ---------------------------------------------------------------------------
__global__ __launch_bounds__(256) void omix(
    const float* __restrict__ O_v, const float* __restrict__ O_a,
    const float* __restrict__ kvv_w, const float* __restrict__ kva_w,
    float* __restrict__ o_v, float* __restrict__ o_a)
{
  __shared__ float sAt[64][20];
  __shared__ float sW[64][64];

  const int z = blockIdx.z;
  const float* Ob = z ? O_a : O_v;
  const float* kvw = z ? kva_w : kvv_w;
  float* oo = z ? o_a : o_v;

  const int rt = blockIdx.x;
  const int h = blockIdx.y;
  const int t = threadIdx.x;
  const int g = t >> 6;
  const int c = t & 63;

  float acc[4] = {0.f, 0.f, 0.f, 0.f};

  for (int ks = 0; ks < 12; ++ks) {
    {
      int r = t >> 4;
      int c4 = (t & 15) * 4;
      int rl = rt * 16 + r;
      int arow = (rl >> 2) * 48 + h * 4 + (rl & 3);
      float4 v = *(const float4*)(Ob + (size_t)arow * 768 + ks * 64 + c4);
      sAt[c4 + 0][r] = v.x;
      sAt[c4 + 1][r] = v.y;
      sAt[c4 + 2][r] = v.z;
      sAt[c4 + 3][r] = v.w;
    }
#pragma unroll
    for (int u = 0; u < 4; ++u) {
      int unit = t + u * 256;
      int k = unit >> 4;
      int c4 = (unit & 15) * 4;
      *(float4*)&sW[k][c4] = *(const float4*)(kvw + (size_t)(ks * 64 + k) * 1536 + 768 + h * 64 + c4);
    }
    __syncthreads();
#pragma unroll 8
    for (int k = 0; k < 64; ++k) {
      float4 a4 = *(const float4*)&sAt[k][g * 4];
      float w = sW[k][c];
      acc[0] += a4.x * w;
      acc[1] += a4.y * w;
      acc[2] += a4.z * w;
      acc[3] += a4.w * w;
    }
    __syncthreads();
  }

#pragma unroll
  for (int rr = 0; rr < 4; ++rr) {
    int rl = rt * 16 + g * 4 + rr;
    oo[(size_t)rl * 768 + h * 64 + c] = acc[rr];
  }
}

// ---------------------------------------------------------------------------
// Fusion attention. grid (12, 64).
// ---------------------------------------------------------------------------
__global__ __launch_bounds__(256) void fusion_attn(
    const float* __restrict__ Qf,
    const float* __restrict__ K1, const float* __restrict__ K2,
    const float* __restrict__ V1, const float* __restrict__ V2,
    float* __restrict__ Of,
    float* __restrict__ AttnOut)
{
  const int h = blockIdx.x;
  const int b = blockIdx.y;
  const int t = threadIdx.x;
  const int lane = t & 63;
  const int wave = t >> 6;

  __shared__ float sQ[8][64];
  __shared__ float sK1[4][64], sK2[4][64], sV1[4][64], sV2[4][64];
  __shared__ float sP[8][16];

  for (int idx = t; idx < 512; idx += 256)
    sQ[idx >> 6][idx & 63] = Qf[((size_t)(b * 8 + (idx >> 6))) * 768 + h * 64 + (idx & 63)];
  {
    size_t base = ((size_t)(b * 4 + wave)) * 768 + h * 64 + lane;
    sK1[wave][lane] = K1[base];
    sK2[wave][lane] = K2[base];
    sV1[wave][lane] = V1[base];
    sV2[wave][lane] = V2[base];
  }
  __syncthreads();

  if (t < 128) {
    int qi = t >> 4, m = t & 15, iv = m >> 2, ja = m & 3;
    float s = 0.f;
#pragma unroll
    for (int d = 0; d < 64; ++d) s += sQ[qi][d] * (sK1[iv][d] + sK2[ja][d]);
    s *= 0.125f;
    float mx = s;
#pragma unroll
    for (int off = 8; off > 0; off >>= 1) mx = fmaxf(mx, __shfl_xor(mx, off, 16));
    float p = __expf(s - mx);
    float l = p;
#pragma unroll
    for (int off = 8; off > 0; off >>= 1) l += __shfl_xor(l, off, 16);
    p = p / l;
    sP[qi][m] = p;
    AttnOut[(((size_t)b * 12 + h) * 8 + qi) * 16 + m] = p;
  }
  __syncthreads();

  for (int idx = t; idx < 512; idx += 256) {
    int qi = idx >> 6, d = idx & 63;
    float o = 0.f;
#pragma unroll
    for (int m = 0; m < 16; ++m) o += sP[qi][m] * (sV1[m >> 2][d] + sV2[m & 3][d]);
    Of[((size_t)(b * 8 + qi)) * 768 + h * 64 + d] = o;
  }
}

// ---------------------------------------------------------------------------
extern "C" void kernel_launch(void* const* d_in, const int* in_sizes, int n_in,
                              void* d_out, int out_size, void* d_ws, size_t ws_size,
                              hipStream_t stream)
{
  const float* xmm     = (const float*)d_in[0];
  const float* xv      = (const float*)d_in[1];
  const float* xa      = (const float*)d_in[2];
  const float* qv_w    = (const float*)d_in[3];
  const float* kvv_w   = (const float*)d_in[4];
  const float* projv_w = (const float*)d_in[5];
  const float* projv_b = (const float*)d_in[6];
  const float* qa_w    = (const float*)d_in[7];
  const float* kva_w   = (const float*)d_in[8];
  const float* proja_w = (const float*)d_in[9];
  const float* proja_b = (const float*)d_in[10];
  const float* fq_w    = (const float*)d_in[11];
  const float* fk_w    = (const float*)d_in[12];
  const float* fv_w    = (const float*)d_in[13];
  const float* fproj_w = (const float*)d_in[14];
  const float* fproj_b = (const float*)d_in[15];

  float* out0 = (float*)d_out;                       // 64 x 16 x 768
  float* out1 = out0 + (size_t)64 * 16 * 768;        // 64 x 12 x 8 x 16

  char* ws = (char*)d_ws;
  size_t off = 0;
  float* q_v  = (float*)(ws + off); off += (size_t)256 * 768 * 4;
  float* q_a  = (float*)(ws + off); off += (size_t)256 * 768 * 4;
  float* q_f  = (float*)(ws + off); off += (size_t)512 * 768 * 4;
  u16*   Qt_v = (u16*)(ws + off);   off += (size_t)64 * 48 * 768 * 2;
  u16*   Qt_a = (u16*)(ws + off);   off += (size_t)64 * 48 * 768 * 2;
  float* S_v  = (float*)(ws + off); off += (size_t)64 * 48 * 784 * 4;
  float* S_a  = (float*)(ws + off); off += (size_t)64 * 48 * 512 * 4;
  u16*   P_v  = (u16*)(ws + off);   off += (size_t)64 * 48 * 832 * 2;
  u16*   P_a  = (u16*)(ws + off);   off += (size_t)64 * 48 * 512 * 2;
  float* O_v  = (float*)(ws + off); off += (size_t)64 * 48 * 768 * 4;
  float* O_a  = (float*)(ws + off); off += (size_t)64 * 48 * 768 * 4;
  float* o_v  = (float*)(ws + off); off += (size_t)256 * 768 * 4;
  float* o_a  = (float*)(ws + off); off += (size_t)256 * 768 * 4;
  float* kbase = (float*)(ws + off); off += (size_t)4 * 256 * 768 * 4;  // k1,k2,v1,v2
  float* o_f  = (float*)(ws + off); off += (size_t)512 * 768 * 4;

  float* k1 = kbase;
  float* k2 = kbase + (size_t)256 * 768;
  float* v1 = kbase + (size_t)2 * 256 * 768;
  float* v2 = kbase + (size_t)3 * 256 * 768;

  qproj<<<dim3(64, 12), 256, 0, stream>>>(xmm, qv_w, qa_w, fq_w, q_v, q_a, q_f);
  qtilde<<<dim3(16, 12, 24), 256, 0, stream>>>(q_v, q_a, kvv_w, kva_w, Qt_v, Qt_a);
  attn_logits<<<dim3(7, 64, 2), 256, 0, stream>>>(Qt_v, Qt_a, xv, xa, S_v, S_a);
  softmax_p<<<dim3(12, 64, 2), 256, 0, stream>>>(S_v, S_a, P_v, P_a);
  attn_px<<<dim3(6, 64, 2), 256, 0, stream>>>(P_v, P_a, xv, xa, O_v, O_a);
  omix<<<dim3(16, 12, 2), 256, 0, stream>>>(O_v, O_a, kvv_w, kva_w, o_v, o_a);
  proj2<<<dim3(16, 12, 2), 256, 0, stream>>>(o_v, o_a, projv_w, projv_b, proja_w, proja_b, out0);
  fkv<<<dim3(16, 12, 4), 256, 0, stream>>>(out0, fk_w, fv_w, kbase);
  fusion_attn<<<dim3(12, 64), 256, 0, stream>>>(q_f, k1, k2, v1, v2, o_f, out1);
  fproj<<<dim3(32, 12), 256, 0, stream>>>(o_f, fproj_w, fproj_b, out0);
}

// Round 4
// 592.352 us; speedup vs baseline: 1.0436x; 1.0268x over previous
//
#include <hip/hip_runtime.h>
#include <stdint.h>

typedef unsigned short u16;
typedef unsigned int u32;
typedef __attribute__((ext_vector_type(8))) short short8;
typedef __attribute__((ext_vector_type(4))) float floatx4;

// B=64, DIM=768, H=12, HEAD=64, SCALE=0.125
// xv: 64x784x768 f32, xa: 64x512x768 f32, xmm: 64x16x768 f32.

__device__ __forceinline__ u16 f2bf_rne(float f) {
  u32 u = __float_as_uint(f);
  return (u16)((u + 0x7fffu + ((u >> 16) & 1u)) >> 16);
}
// pack two f32 bit-patterns -> (bf16(a) | bf16(b)<<16)
__device__ __forceinline__ u32 pack_rne_u(u32 a, u32 b) {
  a += 0x7fffu + ((a >> 16) & 1u);
  b += 0x7fffu + ((b >> 16) & 1u);
  return __builtin_amdgcn_perm(b, a, 0x07060302u);
}
// 8 f32 (two uint4 bit-pattern vectors) -> short8 of bf16
__device__ __forceinline__ short8 pack8(uint4 a, uint4 b) {
  union { u32 u[4]; short8 s; } cv;
  cv.u[0] = pack_rne_u(a.x, a.y);
  cv.u[1] = pack_rne_u(a.z, a.w);
  cv.u[2] = pack_rne_u(b.x, b.y);
  cv.u[3] = pack_rne_u(b.z, b.w);
  return cv.s;
}
__device__ __forceinline__ short8 as_s8(uint4 v) {
  union { uint4 u; short8 s; } c;
  c.u = v;
  return c.s;
}

// Raw barrier that does NOT drain vmcnt.
__device__ __forceinline__ void block_sync_lds() {
  asm volatile("s_waitcnt lgkmcnt(0)" ::: "memory");
  __builtin_amdgcn_s_barrier();
  asm volatile("" ::: "memory");
}

// ---------------------------------------------------------------------------
// Shared small-GEMM body: C = rowmap(A) @ W (+bias). W 768x768 row-major.
// ---------------------------------------------------------------------------
__device__ __forceinline__ void sg_body(
    float (*sAt)[20], float (*sW)[64],
    const float* __restrict__ A, int a_pitch, int a_rb, int a_off,
    const float* __restrict__ W, const float* __restrict__ bias,
    float* __restrict__ Cout, int c_pitch, int c_rb, int c_off,
    int rt, int n0)
{
  const int t = threadIdx.x;
  const int g = t >> 6;
  const int c = t & 63;

  float acc[4] = {0.f, 0.f, 0.f, 0.f};

  for (int ks = 0; ks < 12; ++ks) {
    {
      int r = t >> 4;
      int c4 = (t & 15) * 4;
      int lr = rt * 16 + r;
      int grow = (lr / a_rb) * a_pitch + a_off + (lr % a_rb);
      float4 v = *(const float4*)(A + (size_t)grow * 768 + ks * 64 + c4);
      sAt[c4 + 0][r] = v.x;
      sAt[c4 + 1][r] = v.y;
      sAt[c4 + 2][r] = v.z;
      sAt[c4 + 3][r] = v.w;
    }
#pragma unroll
    for (int u = 0; u < 4; ++u) {
      int unit = t + u * 256;
      int r = unit >> 4;
      int c4 = (unit & 15) * 4;
      *(float4*)&sW[r][c4] = *(const float4*)(W + (size_t)(ks * 64 + r) * 768 + n0 + c4);
    }
    __syncthreads();
#pragma unroll 8
    for (int k = 0; k < 64; ++k) {
      float4 a4 = *(const float4*)&sAt[k][g * 4];
      float w = sW[k][c];
      acc[0] += a4.x * w;
      acc[1] += a4.y * w;
      acc[2] += a4.z * w;
      acc[3] += a4.w * w;
    }
    __syncthreads();
  }

  float bs = bias ? bias[n0 + c] : 0.f;
#pragma unroll
  for (int rr = 0; rr < 4; ++rr) {
    int lr = rt * 16 + g * 4 + rr;
    int grow = (lr / c_rb) * c_pitch + c_off + (lr % c_rb);
    Cout[(size_t)grow * 768 + n0 + c] = acc[rr] + bs;
  }
}

// qproj: q_v / q_a / q_f in one launch. grid (64, 12).
__global__ __launch_bounds__(256) void qproj(
    const float* __restrict__ xmm,
    const float* __restrict__ qv_w, const float* __restrict__ qa_w,
    const float* __restrict__ fq_w,
    float* __restrict__ q_v, float* __restrict__ q_a, float* __restrict__ q_f)
{
  __shared__ float sAt[64][20];
  __shared__ float sW[64][64];
  int rt = blockIdx.x;
  int n0 = blockIdx.y * 64;
  if (rt < 16)
    sg_body(sAt, sW, xmm, 16, 4, 8, qv_w, nullptr, q_v, 4, 4, 0, rt, n0);
  else if (rt < 32)
    sg_body(sAt, sW, xmm, 16, 4, 12, qa_w, nullptr, q_a, 4, 4, 0, rt - 16, n0);
  else
    sg_body(sAt, sW, xmm, 16, 8, 0, fq_w, nullptr, q_f, 8, 8, 0, rt - 32, n0);
}

// proj v/a fused. grid (16, 12, 2).
__global__ __launch_bounds__(256) void proj2(
    const float* __restrict__ o_v, const float* __restrict__ o_a,
    const float* __restrict__ projv_w, const float* __restrict__ projv_b,
    const float* __restrict__ proja_w, const float* __restrict__ proja_b,
    float* __restrict__ out0)
{
  __shared__ float sAt[64][20];
  __shared__ float sW[64][64];
  int z = blockIdx.z;
  sg_body(sAt, sW, z ? o_a : o_v, 4, 4, 0,
          z ? proja_w : projv_w, z ? proja_b : projv_b,
          out0, 16, 4, z ? 12 : 8, blockIdx.x, blockIdx.y * 64);
}

// fkv: k1,k2,v1,v2 in one launch. grid (16, 12, 4). dsts contiguous.
__global__ __launch_bounds__(256) void fkv(
    const float* __restrict__ out0,
    const float* __restrict__ fk_w, const float* __restrict__ fv_w,
    float* __restrict__ kbase)
{
  __shared__ float sAt[64][20];
  __shared__ float sW[64][64];
  int z = blockIdx.z;
  const float* W = (z < 2) ? (fk_w + (size_t)(z & 1) * 768 * 768)
                           : (fv_w + (size_t)(z & 1) * 768 * 768);
  int a_off = (z & 1) ? 12 : 8;
  sg_body(sAt, sW, out0, 16, 4, a_off, W, nullptr,
          kbase + (size_t)z * 256 * 768, 4, 4, 0, blockIdx.x, blockIdx.y * 64);
}

// fproj. grid (32, 12).
__global__ __launch_bounds__(256) void fproj(
    const float* __restrict__ o_f,
    const float* __restrict__ fproj_w, const float* __restrict__ fproj_b,
    float* __restrict__ out0)
{
  __shared__ float sAt[64][20];
  __shared__ float sW[64][64];
  sg_body(sAt, sW, o_f, 8, 8, 0, fproj_w, fproj_b, out0, 16, 8, 0,
          blockIdx.x, blockIdx.y * 64);
}

// ---------------------------------------------------------------------------
// qtilde: Qt[b, h*4+qi, d] = sum_e q[b*4+qi, h*64+e] * kvw[d, h*64+e]  (bf16)
// grid (rt=16, nt=12, z=24): z = path*12 + h.
// ---------------------------------------------------------------------------
__global__ __launch_bounds__(256) void qtilde(
    const float* __restrict__ q_v, const float* __restrict__ q_a,
    const float* __restrict__ kvv_w, const float* __restrict__ kva_w,
    u16* __restrict__ Qt_v, u16* __restrict__ Qt_a)
{
  __shared__ float sAt[64][20];
  __shared__ float sW[64][65];

  const int rt = blockIdx.x;
  const int nt = blockIdx.y;
  const int path = blockIdx.z / 12;
  const int h = blockIdx.z % 12;
  const float* q = path ? q_a : q_v;
  const float* kvw = path ? kva_w : kvv_w;
  u16* Qt = path ? Qt_a : Qt_v;

  const int t = threadIdx.x;
  const int g = t >> 6;
  const int c = t & 63;
  const int n0 = nt * 64;

  {
    int r = t >> 4;
    int c4 = (t & 15) * 4;
    float4 v = *(const float4*)(q + (size_t)(rt * 16 + r) * 768 + h * 64 + c4);
    sAt[c4 + 0][r] = v.x;
    sAt[c4 + 1][r] = v.y;
    sAt[c4 + 2][r] = v.z;
    sAt[c4 + 3][r] = v.w;
  }
#pragma unroll
  for (int u = 0; u < 4; ++u) {
    int unit = t + u * 256;
    int d = unit >> 4;
    int c4 = (unit & 15) * 4;
    float4 v = *(const float4*)(kvw + (size_t)(n0 + d) * 1536 + h * 64 + c4);
    sW[d][c4 + 0] = v.x;
    sW[d][c4 + 1] = v.y;
    sW[d][c4 + 2] = v.z;
    sW[d][c4 + 3] = v.w;
  }
  __syncthreads();

  float acc[4] = {0.f, 0.f, 0.f, 0.f};
#pragma unroll 16
  for (int e = 0; e < 64; ++e) {
    float4 a4 = *(const float4*)&sAt[e][g * 4];
    float w = sW[c][e];
    acc[0] += a4.x * w;
    acc[1] += a4.y * w;
    acc[2] += a4.z * w;
    acc[3] += a4.w * w;
  }
#pragma unroll
  for (int rr = 0; rr < 4; ++rr) {
    int rl = rt * 16 + g * 4 + rr;
    Qt[((size_t)(rl >> 2) * 48 + h * 4 + (rl & 3)) * 768 + n0 + c] = f2bf_rne(acc[rr]);
  }
}

// ---------------------------------------------------------------------------
// attn_logits v5: LDS-free direct-MFMA with ASM-controlled deep pipeline.
// All VMEM in the main loop is inline-asm global_load_dwordx4 (saddr +
// voffset + compile-time offset imm), depth-4 ring: 28 loads (28 KB/wave)
// outstanding, consumed with hand-counted s_waitcnt vmcnt(21) (never 0
// until the tail) + sched_barrier(0) fences. Compiler cannot sink or
// drain the pipeline. grid (7, 64, 2); 24 KB/wave in flight during MFMA.
// ---------------------------------------------------------------------------
__global__ __launch_bounds__(256, 2) void attn_logits(
    const u16* __restrict__ Qt_v, const u16* __restrict__ Qt_a,
    const float* __restrict__ Xv, const float* __restrict__ Xa,
    float* __restrict__ Sv, float* __restrict__ Sa)
{
  const int z = blockIdx.z;
  const int jt = blockIdx.x;
  if (z == 1 && jt >= 4) return;
  const u16* Qt = z ? Qt_a : Qt_v;
  const float* X = z ? Xa : Xv;
  float* S = z ? Sa : Sv;
  const int N2 = z ? 512 : 784;

  const int t = threadIdx.x;
  const int lane = t & 63;
  const int wave = t >> 6;
  const int b = blockIdx.y;
  const int j0 = jt * 128;
  const char* Qb8 = (const char*)(Qt + (size_t)b * 48 * 768);
  const char* Xb8 = (const char*)(X + (size_t)b * N2 * 768);

  const int ql = lane & 15;
  const int qs = lane >> 4;

  int row0 = j0 + wave * 32 + ql;   // jj = 0
  int row1 = row0 + 16;             // jj = 1
  if (row0 > N2 - 1) row0 = N2 - 1;
  if (row1 > N2 - 1) row1 = N2 - 1;
  // byte voffsets; per-kk deltas are compile-time offset: immediates
  const u32 voffX0 = (u32)(row0 * 3072 + qs * 32);
  const u32 voffX1 = (u32)(row1 * 3072 + qs * 32);
  const u32 voffQ0 = (u32)((0 * 16 + ql) * 1536 + qs * 16);
  const u32 voffQ1 = (u32)((1 * 16 + ql) * 1536 + qs * 16);
  const u32 voffQ2 = (u32)((2 * 16 + ql) * 1536 + qs * 16);

  floatx4 acc[3][2];
#pragma unroll
  for (int i = 0; i < 3; ++i)
#pragma unroll
    for (int j = 0; j < 2; ++j) acc[i][j] = (floatx4){0.f, 0.f, 0.f, 0.f};

  uint4 xr[4][4];   // ring: [kk&3][x0a,x0b,x1a,x1b]
  uint4 qu[4][3];   // ring: [kk&3][i]

#define AL5_GL(DST, VOFF, BASE, IMM)                                           \
  asm volatile("global_load_dwordx4 %0, %1, %2 offset:%3"                      \
               : "=v"(DST) : "v"(VOFF), "s"(BASE), "n"(IMM));

#define AL5_ISSUE(K)                                                           \
  do {                                                                         \
    AL5_GL(xr[(K) & 3][0], voffX0, Xb8, (K) * 128)                             \
    AL5_GL(xr[(K) & 3][1], voffX0, Xb8, (K) * 128 + 16)                        \
    AL5_GL(xr[(K) & 3][2], voffX1, Xb8, (K) * 128)                             \
    AL5_GL(xr[(K) & 3][3], voffX1, Xb8, (K) * 128 + 16)                        \
    AL5_GL(qu[(K) & 3][0], voffQ0, Qb8, (K) * 64)                              \
    AL5_GL(qu[(K) & 3][1], voffQ1, Qb8, (K) * 64)                              \
    AL5_GL(qu[(K) & 3][2], voffQ2, Qb8, (K) * 64)                              \
  } while (0)

#define AL5_STEP(K, W)                                                         \
  do {                                                                         \
    asm volatile("s_waitcnt vmcnt(%0)" :: "n"(W));                             \
    __builtin_amdgcn_sched_barrier(0);                                         \
    short8 bf0 = pack8(xr[(K) & 3][0], xr[(K) & 3][1]);                        \
    short8 bf1 = pack8(xr[(K) & 3][2], xr[(K) & 3][3]);                        \
    short8 q0 = as_s8(qu[(K) & 3][0]);                                         \
    short8 q1 = as_s8(qu[(K) & 3][1]);                                         \
    short8 q2 = as_s8(qu[(K) & 3][2]);                                         \
    acc[0][0] = __builtin_amdgcn_mfma_f32_16x16x32_bf16(q0, bf0, acc[0][0], 0, 0, 0); \
    acc[0][1] = __builtin_amdgcn_mfma_f32_16x16x32_bf16(q0, bf1, acc[0][1], 0, 0, 0); \
    acc[1][0] = __builtin_amdgcn_mfma_f32_16x16x32_bf16(q1, bf0, acc[1][0], 0, 0, 0); \
    acc[1][1] = __builtin_amdgcn_mfma_f32_16x16x32_bf16(q1, bf1, acc[1][1], 0, 0, 0); \
    acc[2][0] = __builtin_amdgcn_mfma_f32_16x16x32_bf16(q2, bf0, acc[2][0], 0, 0, 0); \
    acc[2][1] = __builtin_amdgcn_mfma_f32_16x16x32_bf16(q2, bf1, acc[2][1], 0, 0, 0); \
    if ((K) + 4 < 24) AL5_ISSUE((K) + 4);                                      \
  } while (0)

  // prologue: fill the depth-4 ring (28 loads outstanding)
  AL5_ISSUE(0);
  AL5_ISSUE(1);
  AL5_ISSUE(2);
  AL5_ISSUE(3);

  AL5_STEP(0, 21);  AL5_STEP(1, 21);  AL5_STEP(2, 21);  AL5_STEP(3, 21);
  AL5_STEP(4, 21);  AL5_STEP(5, 21);  AL5_STEP(6, 21);  AL5_STEP(7, 21);
  AL5_STEP(8, 21);  AL5_STEP(9, 21);  AL5_STEP(10, 21); AL5_STEP(11, 21);
  AL5_STEP(12, 21); AL5_STEP(13, 21); AL5_STEP(14, 21); AL5_STEP(15, 21);
  AL5_STEP(16, 21); AL5_STEP(17, 21); AL5_STEP(18, 21); AL5_STEP(19, 21);
  AL5_STEP(20, 21); AL5_STEP(21, 14); AL5_STEP(22, 7);  AL5_STEP(23, 0);

#undef AL5_GL
#undef AL5_ISSUE
#undef AL5_STEP

  const int quad = lane >> 4;
  const int lc = lane & 15;
#pragma unroll
  for (int i = 0; i < 3; ++i)
#pragma unroll
    for (int jj = 0; jj < 2; ++jj) {
      int col = j0 + wave * 32 + jj * 16 + lc;
      if (col < N2) {
        int row0s = i * 16 + quad * 4;
#pragma unroll
        for (int r = 0; r < 4; ++r)
          S[((size_t)b * 48 + row0s + r) * N2 + col] = acc[i][jj][r] * 0.125f;
      }
    }
}

// ---------------------------------------------------------------------------
// softmax_p: P = softmax(S) bf16, zero-padded to N2p. grid (12, 64, 2).
// ---------------------------------------------------------------------------
__global__ __launch_bounds__(256) void softmax_p(
    const float* __restrict__ Sv, const float* __restrict__ Sa,
    u16* __restrict__ Pv, u16* __restrict__ Pa)
{
  const int z = blockIdx.z;
  const float* S = z ? Sa : Sv;
  u16* P = z ? Pa : Pv;
  const int N2 = z ? 512 : 784;
  const int N2p = z ? 512 : 832;

  const int hh = blockIdx.x;
  const int b = blockIdx.y;
  const int t = threadIdx.x;
  const int lane = t & 63;
  const int wave = t >> 6;
  const int row = hh * 4 + wave;
  const float* Srow = S + ((size_t)b * 48 + row) * N2;
  u16* Prow = P + ((size_t)b * 48 + row) * N2p;

  float m = -1e30f;
  for (int j = lane; j < N2; j += 64) m = fmaxf(m, Srow[j]);
#pragma unroll
  for (int off = 32; off > 0; off >>= 1) m = fmaxf(m, __shfl_xor(m, off));

  float e[13];
  float l = 0.f;
  int cnt = 0;
  for (int j = lane; j < N2; j += 64) {
    float p = __expf(Srow[j] - m);
    e[cnt++] = p;
    l += p;
  }
#pragma unroll
  for (int off = 32; off > 0; off >>= 1) l += __shfl_xor(l, off);
  float inv = 1.0f / l;

  cnt = 0;
  for (int j = lane; j < N2; j += 64) Prow[j] = f2bf_rne(e[cnt++] * inv);
  for (int j = N2 + lane; j < N2p; j += 64) Prow[j] = 0;
}

// ---------------------------------------------------------------------------
// attn_px: O[b,i,n] = (P_b @ X_b)[i,n]. grid (6, 64, 2).  (unchanged control)
// ---------------------------------------------------------------------------
__global__ __launch_bounds__(256) void attn_px(
    const u16* __restrict__ Pv, const u16* __restrict__ Pa,
    const float* __restrict__ Xv, const float* __restrict__ Xa,
    float* __restrict__ Ov, float* __restrict__ Oa)
{
  const int z = blockIdx.z;
  const u16* P = z ? Pa : Pv;
  const float* X = z ? Xa : Xv;
  float* O = z ? Oa : Ov;
  const int N2 = z ? 512 : 784;
  const int N2p = z ? 512 : 832;

  __shared__ __align__(16) u16 sXT[2][128 * 72];  // 36 KiB double-buffered

  const int t = threadIdx.x;
  const int lane = t & 63;
  const int wave = t >> 6;
  const int nt = blockIdx.x;
  const int b = blockIdx.y;
  const int n0 = nt * 128;
  const u16* Pb = P + (size_t)b * 48 * N2p;
  const float* Xb = X + (size_t)b * N2 * 768;
  const int Ks = N2p >> 6;

  const int jp0 = t >> 5;        // j-pair index (+ u*8)
  const int nq4 = (t & 31) * 4;  // n quad base
  const int qrow0 = lane & 15;
  const int qcb = (lane >> 4) * 8;

  floatx4 acc[3][2];
#pragma unroll
  for (int i = 0; i < 3; ++i)
#pragma unroll
    for (int j = 0; j < 2; ++j) acc[i][j] = (floatx4){0.f, 0.f, 0.f, 0.f};

  uint4 xA[4][2], xB[4][2];
  short8 qr[3][2];

#define PX_LOADX(dst, ks_)                                                     \
  do {                                                                         \
    _Pragma("unroll") for (int u = 0; u < 4; ++u) {                            \
      int j_ = (ks_) * 64 + (jp0 + u * 8) * 2;                                 \
      uint4 a0_ = {0u, 0u, 0u, 0u}, a1_ = {0u, 0u, 0u, 0u};                    \
      if (j_ < N2)                                                             \
        a0_ = *(const uint4*)(Xb + (size_t)j_ * 768 + n0 + nq4);               \
      if (j_ + 1 < N2)                                                         \
        a1_ = *(const uint4*)(Xb + (size_t)(j_ + 1) * 768 + n0 + nq4);         \
      dst[u][0] = a0_;                                                         \
      dst[u][1] = a1_;                                                         \
    }                                                                          \
  } while (0)

#define PX_LOADP(ks_)                                                          \
  do {                                                                         \
    _Pragma("unroll") for (int i = 0; i < 3; ++i)                              \
      _Pragma("unroll") for (int kk = 0; kk < 2; ++kk)                         \
        qr[i][kk] = *(const short8*)(Pb + (size_t)(i * 16 + qrow0) * N2p +     \
                                     (ks_) * 64 + kk * 32 + qcb);              \
  } while (0)

#define PX_WRITEX(src, bufp)                                                   \
  do {                                                                         \
    _Pragma("unroll") for (int u = 0; u < 4; ++u) {                            \
      int jl_ = (jp0 + u * 8) * 2;                                             \
      u32 w0_ = pack_rne_u(src[u][0].x, src[u][1].x);                          \
      u32 w1_ = pack_rne_u(src[u][0].y, src[u][1].y);                          \
      u32 w2_ = pack_rne_u(src[u][0].z, src[u][1].z);                          \
      u32 w3_ = pack_rne_u(src[u][0].w, src[u][1].w);                          \
      _Pragma("unroll") for (int m_ = 0; m_ < 4; ++m_) {                       \
        int n_ = nq4 + m_;                                                     \
        int sw_ = (((n_ >> 2) & 7) ^ ((n_ & 3) << 1)) * 8;                     \
        u32 wv_ = (m_ == 0) ? w0_ : (m_ == 1) ? w1_ : (m_ == 2) ? w2_ : w3_;   \
        *(u32*)((bufp) + n_ * 72 + (jl_ ^ sw_)) = wv_;                         \
      }                                                                        \
    }                                                                          \
  } while (0)

#define PX_COMPUTE(bufp)                                                       \
  do {                                                                         \
    _Pragma("unroll") for (int kk = 0; kk < 2; ++kk) {                         \
      _Pragma("unroll") for (int jj = 0; jj < 2; ++jj) {                       \
        int n_ = wave * 32 + jj * 16 + qrow0;                                  \
        int sw_ = (((n_ >> 2) & 7) ^ ((n_ & 3) << 1)) * 8;                     \
        int kb_ = kk * 32 + qcb;                                               \
        short8 bfr_ = *(const short8*)((bufp) + n_ * 72 + (kb_ ^ sw_));        \
        _Pragma("unroll") for (int i = 0; i < 3; ++i)                          \
          acc[i][jj] = __builtin_amdgcn_mfma_f32_16x16x32_bf16(                \
              qr[i][kk], bfr_, acc[i][jj], 0, 0, 0);                           \
      }                                                                        \
    }                                                                          \
  } while (0)

  u16* sT0 = &sXT[0][0];
  u16* sT1 = &sXT[1][0];

  PX_LOADX(xA, 0);
  PX_LOADP(0);
  int ks = 0;
  for (;;) {
    int more0 = (ks + 1 < Ks);
    if (more0) PX_LOADX(xB, ks + 1);
    PX_WRITEX(xA, sT0);
    block_sync_lds();
    PX_COMPUTE(sT0);
    if (!more0) break;
    PX_LOADP(ks + 1);
    ++ks;
    int more1 = (ks + 1 < Ks);
    if (more1) PX_LOADX(xA, ks + 1);
    PX_WRITEX(xB, sT1);
    block_sync_lds();
    PX_COMPUTE(sT1);
    if (!more1) break;
    PX_LOADP(ks + 1);
    ++ks;
  }
#undef PX_LOADX
#undef PX_LOADP
#undef PX_WRITEX
#undef PX_COMPUTE

  const int quad = lane >> 4;
  const int lc = lane & 15;
#pragma unroll
  for (int i = 0; i < 3; ++i)
#pragma unroll
    for (int jj = 0; jj < 2; ++jj) {
      int col = n0 + wave * 32 + jj * 16 + lc;
      int row0 = i * 16 + quad * 4;
#pragma unroll
      for (int r = 0; r < 4; ++r)
        O[((size_t)b * 48 + row0 + r) * 768 + col] = acc[i][jj][r];
    }
}

// ---------------------------------------------------------------------------
// omix: o[b*4+qi, h*64+e] = sum_d O[b*48+h*4+qi, d] * kvw[d, 768+h*64+e]
// grid (16, 12, 2).
// ---------------------------------------------------------------------------
__global__ __launch_bounds__(256) void omix(
    const float* __restrict__ O_v, const float* __restrict__ O_a,
    const float* __restrict__ kvv_w, const float* __restrict__ kva_w,
    float* __restrict__ o_v, float* __restrict__ o_a)
{
  __shared__ float sAt[64][20];
  __shared__ float sW[64][64];

  const int z = blockIdx.z;
  const float* Ob = z ? O_a : O_v;
  const float* kvw = z ? kva_w : kvv_w;
  float* oo = z ? o_a : o_v;

  const int rt = blockIdx.x;
  const int h = blockIdx.y;
  const int t = threadIdx.x;
  const int g = t >> 6;
  const int c = t & 63;

  float acc[4] = {0.f, 0.f, 0.f, 0.f};

  for (int ks = 0; ks < 12; ++ks) {
    {
      int r = t >> 4;
      int c4 = (t & 15) * 4;
      int rl = rt * 16 + r;
      int arow = (rl >> 2) * 48 + h * 4 + (rl & 3);
      float4 v = *(const float4*)(Ob + (size_t)arow * 768 + ks * 64 + c4);
      sAt[c4 + 0][r] = v.x;
      sAt[c4 + 1][r] = v.y;
      sAt[c4 + 2][r] = v.z;
      sAt[c4 + 3][r] = v.w;
    }
#pragma unroll
    for (int u = 0; u < 4; ++u) {
      int unit = t + u * 256;
      int k = unit >> 4;
      int c4 = (unit & 15) * 4;
      *(float4*)&sW[k][c4] = *(const float4*)(kvw + (size_t)(ks * 64 + k) * 1536 + 768 + h * 64 + c4);
    }
    __syncthreads();
#pragma unroll 8
    for (int k = 0; k < 64; ++k) {
      float4 a4 = *(const float4*)&sAt[k][g * 4];
      float w = sW[k][c];
      acc[0] += a4.x * w;
      acc[1] += a4.y * w;
      acc[2] += a4.z * w;
      acc[3] += a4.w * w;
    }
    __syncthreads();
  }

#pragma unroll
  for (int rr = 0; rr < 4; ++rr) {
    int rl = rt * 16 + g * 4 + rr;
    oo[(size_t)rl * 768 + h * 64 + c] = acc[rr];
  }
}

// ---------------------------------------------------------------------------
// Fusion attention. grid (12, 64).
// ---------------------------------------------------------------------------
__global__ __launch_bounds__(256) void fusion_attn(
    const float* __restrict__ Qf,
    const float* __restrict__ K1, const float* __restrict__ K2,
    const float* __restrict__ V1, const float* __restrict__ V2,
    float* __restrict__ Of,
    float* __restrict__ AttnOut)
{
  const int h = blockIdx.x;
  const int b = blockIdx.y;
  const int t = threadIdx.x;
  const int lane = t & 63;
  const int wave = t >> 6;

  __shared__ float sQ[8][64];
  __shared__ float sK1[4][64], sK2[4][64], sV1[4][64], sV2[4][64];
  __shared__ float sP[8][16];

  for (int idx = t; idx < 512; idx += 256)
    sQ[idx >> 6][idx & 63] = Qf[((size_t)(b * 8 + (idx >> 6))) * 768 + h * 64 + (idx & 63)];
  {
    size_t base = ((size_t)(b * 4 + wave)) * 768 + h * 64 + lane;
    sK1[wave][lane] = K1[base];
    sK2[wave][lane] = K2[base];
    sV1[wave][lane] = V1[base];
    sV2[wave][lane] = V2[base];
  }
  __syncthreads();

  if (t < 128) {
    int qi = t >> 4, m = t & 15, iv = m >> 2, ja = m & 3;
    float s = 0.f;
#pragma unroll
    for (int d = 0; d < 64; ++d) s += sQ[qi][d] * (sK1[iv][d] + sK2[ja][d]);
    s *= 0.125f;
    float mx = s;
#pragma unroll
    for (int off = 8; off > 0; off >>= 1) mx = fmaxf(mx, __shfl_xor(mx, off, 16));
    float p = __expf(s - mx);
    float l = p;
#pragma unroll
    for (int off = 8; off > 0; off >>= 1) l += __shfl_xor(l, off, 16);
    p = p / l;
    sP[qi][m] = p;
    AttnOut[(((size_t)b * 12 + h) * 8 + qi) * 16 + m] = p;
  }
  __syncthreads();

  for (int idx = t; idx < 512; idx += 256) {
    int qi = idx >> 6, d = idx & 63;
    float o = 0.f;
#pragma unroll
    for (int m = 0; m < 16; ++m) o += sP[qi][m] * (sV1[m >> 2][d] + sV2[m & 3][d]);
    Of[((size_t)(b * 8 + qi)) * 768 + h * 64 + d] = o;
  }
}

// ---------------------------------------------------------------------------
extern "C" void kernel_launch(void* const* d_in, const int* in_sizes, int n_in,
                              void* d_out, int out_size, void* d_ws, size_t ws_size,
                              hipStream_t stream)
{
  const float* xmm     = (const float*)d_in[0];
  const float* xv      = (const float*)d_in[1];
  const float* xa      = (const float*)d_in[2];
  const float* qv_w    = (const float*)d_in[3];
  const float* kvv_w   = (const float*)d_in[4];
  const float* projv_w = (const float*)d_in[5];
  const float* projv_b = (const float*)d_in[6];
  const float* qa_w    = (const float*)d_in[7];
  const float* kva_w   = (const float*)d_in[8];
  const float* proja_w = (const float*)d_in[9];
  const float* proja_b = (const float*)d_in[10];
  const float* fq_w    = (const float*)d_in[11];
  const float* fk_w    = (const float*)d_in[12];
  const float* fv_w    = (const float*)d_in[13];
  const float* fproj_w = (const float*)d_in[14];
  const float* fproj_b = (const float*)d_in[15];

  float* out0 = (float*)d_out;                       // 64 x 16 x 768
  float* out1 = out0 + (size_t)64 * 16 * 768;        // 64 x 12 x 8 x 16

  char* ws = (char*)d_ws;
  size_t off = 0;
  float* q_v  = (float*)(ws + off); off += (size_t)256 * 768 * 4;
  float* q_a  = (float*)(ws + off); off += (size_t)256 * 768 * 4;
  float* q_f  = (float*)(ws + off); off += (size_t)512 * 768 * 4;
  u16*   Qt_v = (u16*)(ws + off);   off += (size_t)64 * 48 * 768 * 2;
  u16*   Qt_a = (u16*)(ws + off);   off += (size_t)64 * 48 * 768 * 2;
  float* S_v  = (float*)(ws + off); off += (size_t)64 * 48 * 784 * 4;
  float* S_a  = (float*)(ws + off); off += (size_t)64 * 48 * 512 * 4;
  u16*   P_v  = (u16*)(ws + off);   off += (size_t)64 * 48 * 832 * 2;
  u16*   P_a  = (u16*)(ws + off);   off += (size_t)64 * 48 * 512 * 2;
  float* O_v  = (float*)(ws + off); off += (size_t)64 * 48 * 768 * 4;
  float* O_a  = (float*)(ws + off); off += (size_t)64 * 48 * 768 * 4;
  float* o_v  = (float*)(ws + off); off += (size_t)256 * 768 * 4;
  float* o_a  = (float*)(ws + off); off += (size_t)256 * 768 * 4;
  float* kbase = (float*)(ws + off); off += (size_t)4 * 256 * 768 * 4;  // k1,k2,v1,v2
  float* o_f  = (float*)(ws + off); off += (size_t)512 * 768 * 4;

  float* k1 = kbase;
  float* k2 = kbase + (size_t)256 * 768;
  float* v1 = kbase + (size_t)2 * 256 * 768;
  float* v2 = kbase + (size_t)3 * 256 * 768;

  qproj<<<dim3(64, 12), 256, 0, stream>>>(xmm, qv_w, qa_w, fq_w, q_v, q_a, q_f);
  qtilde<<<dim3(16, 12, 24), 256, 0, stream>>>(q_v, q_a, kvv_w, kva_w, Qt_v, Qt_a);
  attn_logits<<<dim3(7, 64, 2), 256, 0, stream>>>(Qt_v, Qt_a, xv, xa, S_v, S_a);
  softmax_p<<<dim3(12, 64, 2), 256, 0, stream>>>(S_v, S_a, P_v, P_a);
  attn_px<<<dim3(6, 64, 2), 256, 0, stream>>>(P_v, P_a, xv, xa, O_v, O_a);
  omix<<<dim3(16, 12, 2), 256, 0, stream>>>(O_v, O_a, kvv_w, kva_w, o_v, o_a);
  proj2<<<dim3(16, 12, 2), 256, 0, stream>>>(o_v, o_a, projv_w, projv_b, proja_w, proja_b, out0);
  fkv<<<dim3(16, 12, 4), 256, 0, stream>>>(out0, fk_w, fv_w, kbase);
  fusion_attn<<<dim3(12, 64), 256, 0, stream>>>(q_f, k1, k2, v1, v2, o_f, out1);
  fproj<<<dim3(32, 12), 256, 0, stream>>>(o_f, fproj_w, fproj_b, out0);
}